// Round 1
// baseline (1005.780 us; speedup 1.0000x reference)
//
#include <hip/hip_runtime.h>
#include <hip/hip_bf16.h>
#include <math.h>

// CircularBasisLayer:
//   rbf[e, r]  = env(d) * norm/d * sin((r+1) * pi * d/CUTOFF),  r = 0..15
//   cbf[t, s]  = exp(coeff * (cos_phi[t] - offset_s)^2),        s = 0..7
//   out[t, s*16 + r] = rbf[id3[t], r] * cbf[t, s]               (S-major flatten)
//
// E = 400000, T = 2000000, out = [T, 128] fp32 = 1.024 GB -> write-BW bound.

#define NUM_RADIAL 16
#define NUM_SPHERICAL 8
#define TPB 256

__global__ __launch_bounds__(TPB)
void CircularBasisLayer_kernel(const float* __restrict__ D_ca,
                               const float* __restrict__ cos_phi,
                               const int* __restrict__ id3,
                               float* __restrict__ out,
                               int T) {
    // +1 pad on bes leading dim -> phase-1 writes (stride 17, odd) are conflict-free
    __shared__ float bes[TPB][NUM_RADIAL + 1];    // 17.4 KB
    __shared__ float cbf[TPB][NUM_SPHERICAL + 1]; //  9.2 KB

    const int tid = threadIdx.x;
    const long long t = (long long)blockIdx.x * TPB + tid;

    if (t < T) {
        const int   e  = id3[t];
        const float d  = D_ca[e];        // gather, L2-resident (1.6 MB table)
        const float cp = cos_phi[t];

        const float ds = d * (1.0f / 6.0f);           // d / CUTOFF, in (0.083, 1)
        // polynomial envelope, p = 5: 1 - 21 ds^5 + 35 ds^6 - 15 ds^7
        float ds2 = ds * ds;
        float ds5 = ds2 * ds2 * ds;
        float env = 1.0f + ds5 * (-21.0f + ds * (35.0f + ds * -15.0f));
        env = (ds < 1.0f) ? env : 0.0f;

        const float norm = 0.09622504486493763f;      // sqrt(2 / 6^3)
        const float pref = env * norm / d;
        const float x = 3.14159265358979323846f * ds; // pi * d_scaled

        #pragma unroll
        for (int r = 0; r < NUM_RADIAL; ++r) {
            bes[tid][r] = pref * __sinf((float)(r + 1) * x);
        }

        const float coeff = -6.125f;                  // -0.5 / (2/7)^2
        #pragma unroll
        for (int s = 0; s < NUM_SPHERICAL; ++s) {
            const float off = -1.0f + (float)s * (2.0f / 7.0f);
            const float df  = cp - off;
            cbf[tid][s] = __expf(coeff * df * df);
        }
    }
    __syncthreads();

    // Phase 2: block writes TPB rows x 32 float4, coalesced across lanes.
    // float4 index within block: f = k*TPB + tid  (consecutive lanes ->
    // consecutive 16B segments -> 1 KiB per store instruction per wave).
    float4* __restrict__ out4 = (float4*)out;
    const long long blockBase = (long long)blockIdx.x * (TPB * 32);

    #pragma unroll
    for (int k = 0; k < 32; ++k) {
        const int f    = k * TPB + tid;        // 0 .. 8191
        const int trip = f >> 5;               // local triplet 0..255
        const long long gt = (long long)blockIdx.x * TPB + trip;
        if (gt < T) {
            const int c0 = (f & 31) << 2;      // element col 0..124, mult of 4
            const int s  = c0 >> 4;
            const int r  = c0 & 15;
            const float cv = cbf[trip][s];
            float4 v;
            v.x = bes[trip][r + 0] * cv;
            v.y = bes[trip][r + 1] * cv;
            v.z = bes[trip][r + 2] * cv;
            v.w = bes[trip][r + 3] * cv;
            out4[blockBase + f] = v;
        }
    }
}

extern "C" void kernel_launch(void* const* d_in, const int* in_sizes, int n_in,
                              void* d_out, int out_size, void* d_ws, size_t ws_size,
                              hipStream_t stream) {
    const float* D_ca    = (const float*)d_in[0];
    const float* cos_phi = (const float*)d_in[1];
    const int*   id3     = (const int*)d_in[2];
    float* out = (float*)d_out;

    const int T = in_sizes[1];                 // N_TRIPLETS
    const int blocks = (T + TPB - 1) / TPB;

    CircularBasisLayer_kernel<<<blocks, TPB, 0, stream>>>(D_ca, cos_phi, id3, out, T);
}